// Round 2
// baseline (399.686 us; speedup 1.0000x reference)
//
#include <hip/hip_runtime.h>
#include <hip/hip_bf16.h>
#include <cstdint>

typedef float v4f __attribute__((ext_vector_type(4)));
typedef float v2f __attribute__((ext_vector_type(2)));

// ---------------------------------------------------------------------------
// ws float layout:
//   [0, 122880): wTpad[3][256][160]
//       row c: cols 0..95  = cls, 8 groups of 12 (10 valid: o = g*10+q, q<10)
//              cols 96..159 = reg, o = col-96
//   [122880, 123360): biaspad[3][160], same column mapping
// ---------------------------------------------------------------------------
#define LVL_WSTRIDE 40960
#define BIASPAD_OFF 122880

__global__ __launch_bounds__(256) void prep_weights(
    const float* __restrict__ cw0, const float* __restrict__ cb0,
    const float* __restrict__ rw0, const float* __restrict__ rb0,
    const float* __restrict__ cw1, const float* __restrict__ cb1,
    const float* __restrict__ rw1, const float* __restrict__ rb1,
    const float* __restrict__ cw2, const float* __restrict__ cb2,
    const float* __restrict__ rw2, const float* __restrict__ rb2,
    float* __restrict__ ws)
{
  const int gid = blockIdx.x * 256 + threadIdx.x;
  const float* cws[3] = {cw0, cw1, cw2};
  const float* cbs[3] = {cb0, cb1, cb2};
  const float* rws[3] = {rw0, rw1, rw2};
  const float* rbs[3] = {rb0, rb1, rb2};
  if (gid < 3 * LVL_WSTRIDE) {
    const int l = gid / LVL_WSTRIDE;
    const int rem = gid - l * LVL_WSTRIDE;
    const int c = rem / 160;
    const int j = rem - c * 160;
    float v = 0.f;
    if (j < 96) {
      const int g = j / 12, q = j - g * 12;
      if (q < 10) v = cws[l][(g * 10 + q) * 256 + c];
    } else {
      v = rws[l][(j - 96) * 256 + c];
    }
    ws[gid] = v;
  } else if (gid < 3 * LVL_WSTRIDE + 480) {
    const int i = gid - 3 * LVL_WSTRIDE;
    const int l = i / 160;
    const int j = i - l * 160;
    float v = 0.f;
    if (j < 96) {
      const int g = j / 12, q = j - g * 12;
      if (q < 10) v = cbs[l][g * 10 + q];
    } else {
      v = rbs[l][j - 96];
    }
    ws[BIASPAD_OFF + i] = v;
  }
}

// ---------------------------------------------------------------------------
// Fused head kernel. One block = 128 pixels of one (level, batch).
// Phases: reg GEMM -> DFL/box -> cls GEMM -> LDS out-stage -> coalesced store.
//
// LDS pool (floats):
//   As      [0,     1024)   A-tile [8][128]
//   Bs      [1024,  1792)   B-tile [8][96] (cls) / [8][64] (reg)
//   rstage  [1792,  10496)  reg preds [128][68] (68 = pad to cut bank conflicts)
//   dstage  [10496, 11008)  DFL distances [128][4]
//   ostage  [0,     10752)  output stage [128][84] (aliases As/Bs/rstage/dstage
//                           -- all dead by the time ostage is written)
// ---------------------------------------------------------------------------
__global__ __launch_bounds__(256, 3) void head_kernel(
    const float* __restrict__ cf0, const float* __restrict__ rf0,
    const float* __restrict__ cf1, const float* __restrict__ rf1,
    const float* __restrict__ cf2, const float* __restrict__ rf2,
    const float* __restrict__ ws, float* __restrict__ out)
{
  __shared__ float pool[11008];
  float* const As     = pool;
  float* const Bs     = pool + 1024;
  float* const rstage = pool + 1792;
  float* const dstage = pool + 10496;
  float* const ostage = pool;

  const int t = threadIdx.x;
  const int bid = blockIdx.x;

  int l, r;
  if (bid < 800)       { l = 0; r = bid; }
  else if (bid < 1008) { l = 1; r = bid - 800; }
  else                 { l = 2; r = bid - 1008; }

  const int tiles = (l == 0) ? 50 : (l == 1) ? 13 : 4;
  const int M     = (l == 0) ? 6400 : (l == 1) ? 1600 : 400;
  const int W     = (l == 0) ? 80 : (l == 1) ? 40 : 20;
  const int moff  = (l == 0) ? 0 : (l == 1) ? 6400 : 8000;
  const float sv  = (float)(8 << l);

  const int b    = r / tiles;
  const int tile = r - b * tiles;
  const int m0   = tile * 128;

  const float* const cf   = (l == 0) ? cf0 : (l == 1) ? cf1 : cf2;
  const float* const rf   = (l == 0) ? rf0 : (l == 1) ? rf1 : rf2;
  const float* const wT   = ws + l * LVL_WSTRIDE;
  const float* const bias = ws + BIASPAD_OFF + l * 160;

  const int mg  = t & 31;   // pixel group (4 consecutive pixels)
  const int og  = t >> 5;   // output group 0..7
  const int mg4 = mg * 4;

  // clamped pixel index for A staging (tail tiles re-read the last valid rows;
  // results are masked at store time)
  const int mclamp = min(m0 + mg4, M - 4);

  // ======================= phase R: reg GEMM (64 outs) =====================
  float accR[4][8];
#pragma unroll
  for (int i = 0; i < 4; ++i)
#pragma unroll
    for (int j = 0; j < 8; ++j) accR[i][j] = 0.f;

  const float* const featR = rf + (size_t)b * 256 * (size_t)M;
  for (int ks = 0; ks < 32; ++ks) {
    const int k = ks * 8;
    const v4f av = *(const v4f*)(featR + (size_t)(k + og) * M + mclamp);
    v4f bv;
    if (t < 128) {  // stage B [8][64]: 512 floats
      const int cc = t >> 4, jj = (t & 15) * 4;
      bv = *(const v4f*)(wT + (k + cc) * 160 + 96 + jj);
    }
    __syncthreads();              // prior iteration's compute done
    *(v4f*)&As[t * 4] = av;
    if (t < 128) *(v4f*)&Bs[t * 4] = bv;
    __syncthreads();
#pragma unroll
    for (int cc = 0; cc < 8; ++cc) {
      const v4f a  = *(const v4f*)&As[cc * 128 + mg4];
      const v4f b0 = *(const v4f*)&Bs[cc * 64 + og * 8];
      const v4f b1 = *(const v4f*)&Bs[cc * 64 + og * 8 + 4];
#pragma unroll
      for (int i = 0; i < 4; ++i) {
#pragma unroll
        for (int j = 0; j < 4; ++j) {
          accR[i][j]     += a[i] * b0[j];
          accR[i][j + 4] += a[i] * b1[j];
        }
      }
    }
  }
  __syncthreads();  // last compute's LDS reads done before rstage writes race ahead

  // bias + park reg predictions in LDS
#pragma unroll
  for (int i = 0; i < 4; ++i) {
    const int m = mg4 + i;
#pragma unroll
    for (int j = 0; j < 8; ++j)
      rstage[m * 68 + og * 8 + j] = accR[i][j] + bias[96 + og * 8 + j];
  }
  __syncthreads();

  // ======================= DFL: 512 tasks (m, side), 2 per thread ==========
  float dv0 = 0.f, dv1 = 0.f;
#pragma unroll
  for (int it = 0; it < 2; ++it) {
    const int tau = t + it * 256;
    const int m = tau >> 2, f = tau & 3;
    const float* xp = &rstage[m * 68 + f * 16];
    float x[16];
    *(v4f*)&x[0]  = *(const v4f*)(xp);
    *(v4f*)&x[4]  = *(const v4f*)(xp + 4);
    *(v4f*)&x[8]  = *(const v4f*)(xp + 8);
    *(v4f*)&x[12] = *(const v4f*)(xp + 12);
    float mx = x[0];
#pragma unroll
    for (int q = 1; q < 16; ++q) mx = fmaxf(mx, x[q]);
    float s = 0.f, d = 0.f;
#pragma unroll
    for (int q = 0; q < 16; ++q) {
      const float e = __expf(x[q] - mx);
      s += e;
      d += e * (float)q;
    }
    const float res = d * (16.f / 15.f) / s;  // proj[r] = 16r/15
    if (it == 0) dv0 = res; else dv1 = res;
  }
  dstage[t]       = dv0;
  dstage[t + 256] = dv1;
  __syncthreads();

  // box from anchors (held in registers across the cls GEMM)
  float bx0 = 0.f, by0 = 0.f, bx1 = 0.f, by1 = 0.f;
  if (t < 128) {
    const v4f dd = *(const v4f*)&dstage[t * 4];
    const int mglob = m0 + t;
    const int hh = mglob / W;
    const int wcol = mglob - hh * W;
    const float ax = ((float)wcol + 0.5f) * sv;
    const float ay = ((float)hh + 0.5f) * sv;
    bx0 = ax - dd[0] * sv;
    by0 = ay - dd[1] * sv;
    bx1 = ax + dd[2] * sv;
    by1 = ay + dd[3] * sv;
  }

  // ======================= phase C: cls GEMM (80 outs) =====================
  float accC[4][10];
#pragma unroll
  for (int i = 0; i < 4; ++i)
#pragma unroll
    for (int j = 0; j < 10; ++j) accC[i][j] = 0.f;

  const float* const featC = cf + (size_t)b * 256 * (size_t)M;
  for (int ks = 0; ks < 32; ++ks) {
    const int k = ks * 8;
    const v4f av = *(const v4f*)(featC + (size_t)(k + og) * M + mclamp);
    v4f bv;
    if (t < 192) {  // stage B [8][96]: 768 floats
      const int cc = t / 24;
      const int jj = (t - cc * 24) * 4;
      bv = *(const v4f*)(wT + (k + cc) * 160 + jj);
    }
    __syncthreads();
    *(v4f*)&As[t * 4] = av;
    if (t < 192) *(v4f*)&Bs[t * 4] = bv;
    __syncthreads();
#pragma unroll
    for (int cc = 0; cc < 8; ++cc) {
      const v4f a  = *(const v4f*)&As[cc * 128 + mg4];
      const v4f b0 = *(const v4f*)&Bs[cc * 96 + og * 12];
      const v4f b1 = *(const v4f*)&Bs[cc * 96 + og * 12 + 4];
      const v2f b2 = *(const v2f*)&Bs[cc * 96 + og * 12 + 8];
#pragma unroll
      for (int i = 0; i < 4; ++i) {
#pragma unroll
        for (int j = 0; j < 4; ++j) {
          accC[i][j]     += a[i] * b0[j];
          accC[i][j + 4] += a[i] * b1[j];
        }
        accC[i][8] += a[i] * b2[0];
        accC[i][9] += a[i] * b2[1];
      }
    }
  }
  __syncthreads();  // REQUIRED: ostage aliases As/Bs — last compute must finish

  // ======================= epilogue: sigmoid + assemble rows ===============
#pragma unroll
  for (int i = 0; i < 4; ++i) {
    const int m = mg4 + i;
#pragma unroll
    for (int j = 0; j < 10; ++j) {
      const float z = accC[i][j] + bias[og * 12 + j];
      ostage[m * 84 + og * 10 + j] = 1.f / (1.f + __expf(-z));
    }
  }
  if (t < 128) {
    v4f bb; bb[0] = bx0; bb[1] = by0; bb[2] = bx1; bb[3] = by1;
    *(v4f*)&ostage[t * 84 + 80] = bb;
  }
  __syncthreads();

  // ======================= coalesced store (rows are contiguous) ===========
  float* const obase = out + ((size_t)b * 8400 + moff + m0) * 84;
#pragma unroll
  for (int i = 0; i < 21; ++i) {
    const int p  = i * 256 + t;   // pair index, 5376 pairs = 128*84/2
    const int fe = p * 2;
    const int m  = fe / 84;       // 84 even -> a pair never crosses a row
    if (m0 + m < M) {
      *(v2f*)(obase + fe) = *(const v2f*)&ostage[fe];
    }
  }
}

// ---------------------------------------------------------------------------
extern "C" void kernel_launch(void* const* d_in, const int* in_sizes, int n_in,
                              void* d_out, int out_size, void* d_ws, size_t ws_size,
                              hipStream_t stream) {
  // setup_inputs() dict order (interleaved per level):
  // i*6 + {0: cls_feat, 1: reg_feat, 2: cls_w, 3: cls_b, 4: reg_w, 5: reg_b}
  const float* cf[3]; const float* rff[3];
  const float* cw[3]; const float* cb[3];
  const float* rw[3]; const float* rb[3];
  for (int i = 0; i < 3; ++i) {
    cf[i]  = (const float*)d_in[i * 6 + 0];
    rff[i] = (const float*)d_in[i * 6 + 1];
    cw[i]  = (const float*)d_in[i * 6 + 2];
    cb[i]  = (const float*)d_in[i * 6 + 3];
    rw[i]  = (const float*)d_in[i * 6 + 4];
    rb[i]  = (const float*)d_in[i * 6 + 5];
  }
  float* ws = (float*)d_ws;
  float* o  = (float*)d_out;

  prep_weights<<<dim3(482), dim3(256), 0, stream>>>(
      cw[0], cb[0], rw[0], rb[0],
      cw[1], cb[1], rw[1], rb[1],
      cw[2], cb[2], rw[2], rb[2], ws);

  // blocks: lvl0 50 tiles*16 = 800, lvl1 13*16 = 208, lvl2 4*16 = 64 -> 1072
  head_kernel<<<dim3(1072), dim3(256), 0, stream>>>(
      cf[0], rff[0], cf[1], rff[1], cf[2], rff[2], ws, o);
}

// Round 3
// 352.884 us; speedup vs baseline: 1.1326x; 1.1326x over previous
//
#include <hip/hip_runtime.h>
#include <hip/hip_bf16.h>
#include <cstdint>

typedef float v4f __attribute__((ext_vector_type(4)));
typedef float v2f __attribute__((ext_vector_type(2)));
typedef short s8v __attribute__((ext_vector_type(8)));
typedef unsigned short u16;

// ---------------------------------------------------------------------------
// ws layout (bytes):
//   [0, 442368)        wsB: bf16 MFMA B-fragments, per level (73728 u16):
//                        cls  [ks 0..7][nt 0..4][hl 0..1][lane 0..63][j 0..7]
//                        reg  (offset +40960 u16) [ks][nt 0..3][hl][lane][j]
//                      element: o = nt*16 + (lane&15), k = ks*32 + (lane>>4)*8 + j
//                      hl=0: bf16(w), hl=1: bf16(w - float(bf16(w)))
//   [442368, 444096)   biasf fp32 [3][144]: cls o=0..79, reg at 80+o
// ---------------------------------------------------------------------------
#define WSB_LVL     73728
#define WSB_CLS_SZ  40960
#define BIAS_OFF_B  442368

__device__ __forceinline__ u16 bfbits(float x) {
  return __builtin_bit_cast(u16, __float2bfloat16(x));
}
__device__ __forceinline__ float bff(u16 b) {
  return __builtin_bit_cast(float, ((unsigned int)b) << 16);
}
__device__ __forceinline__ unsigned int packhi(float a, float b) {
  return (unsigned int)bfbits(a) | ((unsigned int)bfbits(b) << 16);
}
__device__ __forceinline__ unsigned int packlo(float a, float b) {
  const float ra = a - bff(bfbits(a));
  const float rb = b - bff(bfbits(b));
  return packhi(ra, rb);
}
__device__ __forceinline__ v4f mfma16(s8v a, s8v b, v4f c) {
  return __builtin_amdgcn_mfma_f32_16x16x32_bf16(a, b, c, 0, 0, 0);
}

// ---------------------------------------------------------------------------
__global__ __launch_bounds__(256) void prep_weights(
    const float* __restrict__ cw0, const float* __restrict__ cb0,
    const float* __restrict__ rw0, const float* __restrict__ rb0,
    const float* __restrict__ cw1, const float* __restrict__ cb1,
    const float* __restrict__ rw1, const float* __restrict__ rb1,
    const float* __restrict__ cw2, const float* __restrict__ cb2,
    const float* __restrict__ rw2, const float* __restrict__ rb2,
    void* __restrict__ wsv)
{
  u16* wsB = (u16*)wsv;
  float* biasf = (float*)((char*)wsv + BIAS_OFF_B);
  const int gid = blockIdx.x * 256 + threadIdx.x;
  const float* cws[3] = {cw0, cw1, cw2};
  const float* cbs[3] = {cb0, cb1, cb2};
  const float* rws[3] = {rw0, rw1, rw2};
  const float* rbs[3] = {rb0, rb1, rb2};

  if (gid < 3 * WSB_LVL) {
    const int l = gid / WSB_LVL;
    int r = gid - l * WSB_LVL;
    const bool cls = r < WSB_CLS_SZ;
    if (!cls) r -= WSB_CLS_SZ;
    const int j    = r & 7;
    const int lane = (r >> 3) & 63;
    const int hl   = (r >> 9) & 1;
    int nt, ks;
    if (cls) { const int v = r >> 10; nt = v % 5; ks = v / 5; }
    else     { nt = (r >> 10) & 3; ks = r >> 12; }
    const int o = nt * 16 + (lane & 15);
    const int k = ks * 32 + (lane >> 4) * 8 + j;
    const float* w = cls ? cws[l] : rws[l];
    const float v = w[o * 256 + k];
    u16 bits;
    if (hl == 0) bits = bfbits(v);
    else         bits = bfbits(v - bff(bfbits(v)));
    wsB[gid] = bits;
  } else if (gid < 3 * WSB_LVL + 432) {
    const int i = gid - 3 * WSB_LVL;
    const int l = i / 144;
    const int o = i - l * 144;
    biasf[l * 144 + o] = (o < 80) ? cbs[l][o] : rbs[l][o - 80];
  }
}

// ---------------------------------------------------------------------------
// Split-bf16 MFMA GEMM over one 128-pixel tile, K=256 (8 K-steps of 32).
// A staged in LDS [128][72 bf16] (hi k0..31, lo at +32); 144B row stride keeps
// ds_read_b128 A-fragment reads bank-uniform (8 words/bank = minimum).
// Prefetch: global loads for ks+1 issued into regs right after the ds_write of
// ks, so their latency hides under compute(ks) (T14 issue-early/write-late).
// B-fragments read directly from global ws (pre-packed per-lane, L2-hot).
// ---------------------------------------------------------------------------
template<int NT>
__device__ __forceinline__ void gemm_accum(const float* __restrict__ feat,
                                           const u16* __restrict__ wB,
                                           u16* Abuf, const int t,
                                           const int m0, const int M,
                                           v4f (&acc)[2][NT])
{
  const int kp   = t & 15;       // k-pair 0..15 (k = 2*kp, 2*kp+1)
  const int mq0  = t >> 4;       // m-quad 0..15 (packet B: +16)
  const int mmA  = min(m0 + mq0 * 4, M - 4);
  const int mmB  = min(m0 + (mq0 + 16) * 4, M - 4);
  const int lane   = t & 63;
  const int lane15 = lane & 15;
  const int kg     = lane >> 4;
  const int mbase  = (t >> 6) * 32;
  unsigned int* AbufW = (unsigned int*)Abuf;
  const int w0 = (mq0 * 4) * 36 + kp;          // uint index, rows j add 36
  const int w1 = ((mq0 + 16) * 4) * 36 + kp;

  v4f r0a = *(const v4f*)(feat + (size_t)(2 * kp) * M + mmA);
  v4f r0b = *(const v4f*)(feat + (size_t)(2 * kp + 1) * M + mmA);
  v4f r1a = *(const v4f*)(feat + (size_t)(2 * kp) * M + mmB);
  v4f r1b = *(const v4f*)(feat + (size_t)(2 * kp + 1) * M + mmB);

#pragma unroll
  for (int ks = 0; ks < 8; ++ks) {
    // ---- stage current K-step into LDS (2-lanes/bank writes: free) ----
#pragma unroll
    for (int j = 0; j < 4; ++j) {
      AbufW[w0 + j * 36]      = packhi(r0a[j], r0b[j]);
      AbufW[w0 + j * 36 + 16] = packlo(r0a[j], r0b[j]);
      AbufW[w1 + j * 36]      = packhi(r1a[j], r1b[j]);
      AbufW[w1 + j * 36 + 16] = packlo(r1a[j], r1b[j]);
    }
    // ---- issue next K-step's global loads (latency hides under compute) ----
    if (ks < 7) {
      const size_t ko = (size_t)((ks + 1) * 32 + 2 * kp) * M;
      r0a = *(const v4f*)(feat + ko + mmA);
      r0b = *(const v4f*)(feat + ko + M + mmA);
      r1a = *(const v4f*)(feat + ko + mmB);
      r1b = *(const v4f*)(feat + ko + M + mmB);
    }
    __syncthreads();
    // ---- A-fragments (ds_read_b128 x4) ----
    const u16* arow0 = Abuf + (mbase + lane15) * 72 + kg * 8;
    const u16* arow1 = Abuf + (mbase + 16 + lane15) * 72 + kg * 8;
    const s8v ahi0 = *(const s8v*)(arow0);
    const s8v alo0 = *(const s8v*)(arow0 + 32);
    const s8v ahi1 = *(const s8v*)(arow1);
    const s8v alo1 = *(const s8v*)(arow1 + 32);
    // ---- B-fragments direct from global (L2-hot) + split-bf16 MFMA ----
#pragma unroll
    for (int nt = 0; nt < NT; ++nt) {
      const u16* bp = wB + (size_t)((ks * NT + nt) * 2) * 512 + lane * 8;
      const s8v bhi = *(const s8v*)(bp);
      const s8v blo = *(const s8v*)(bp + 512);
      acc[0][nt] = mfma16(ahi0, bhi, acc[0][nt]);
      acc[0][nt] = mfma16(ahi0, blo, acc[0][nt]);
      acc[0][nt] = mfma16(alo0, bhi, acc[0][nt]);
      acc[1][nt] = mfma16(ahi1, bhi, acc[1][nt]);
      acc[1][nt] = mfma16(ahi1, blo, acc[1][nt]);
      acc[1][nt] = mfma16(alo1, bhi, acc[1][nt]);
    }
    __syncthreads();   // protects Abuf for next iteration's ds_write
  }
}

// ---------------------------------------------------------------------------
// LDS (bytes):
//   Abuf    [0, 18432)      128 x 72 bf16 A-tile (hi+lo)
//   ostage  [0, 43008)      out stage [128][84] f32 (aliases Abuf; Abuf dead)
//   boxstage[43008, 45056)  box [128][4] f32 (live across cls GEMM)
// ---------------------------------------------------------------------------
__global__ __launch_bounds__(256, 3) void head_kernel(
    const float* __restrict__ cf0, const float* __restrict__ rf0,
    const float* __restrict__ cf1, const float* __restrict__ rf1,
    const float* __restrict__ cf2, const float* __restrict__ rf2,
    const void* __restrict__ wsv, float* __restrict__ out)
{
  __shared__ __align__(16) char smem[45056];
  u16*  Abuf     = (u16*)smem;
  float* ostage   = (float*)smem;
  float* boxstage = (float*)(smem + 43008);

  const u16*  wsB   = (const u16*)wsv;
  const float* biasf = (const float*)((const char*)wsv + BIAS_OFF_B);

  const int t   = threadIdx.x;
  const int bid = blockIdx.x;

  int l, r;
  if (bid < 800)       { l = 0; r = bid; }
  else if (bid < 1008) { l = 1; r = bid - 800; }
  else                 { l = 2; r = bid - 1008; }

  const int tiles = (l == 0) ? 50 : (l == 1) ? 13 : 4;
  const int M     = (l == 0) ? 6400 : (l == 1) ? 1600 : 400;
  const int W     = (l == 0) ? 80 : (l == 1) ? 40 : 20;
  const int moff  = (l == 0) ? 0 : (l == 1) ? 6400 : 8000;
  const float sv  = (float)(8 << l);

  const int b    = r / tiles;
  const int tile = r - b * tiles;
  const int m0   = tile * 128;

  const float* cfL = (l == 0) ? cf0 : (l == 1) ? cf1 : cf2;
  const float* rfL = (l == 0) ? rf0 : (l == 1) ? rf1 : rf2;
  const float* featR = rfL + (size_t)b * 256 * (size_t)M;
  const float* featC = cfL + (size_t)b * 256 * (size_t)M;
  const u16* wBcls = wsB + l * WSB_LVL;
  const u16* wBreg = wsB + l * WSB_LVL + WSB_CLS_SZ;
  const int loff = l * 144;

  const int lane   = t & 63;
  const int lane15 = lane & 15;
  const int kg     = lane >> 4;
  const int mbase  = (t >> 6) * 32;

  // ======================= reg GEMM (64 outs = 4 sides x 16 bins) ==========
  v4f accR[2][4];
#pragma unroll
  for (int mr = 0; mr < 2; ++mr)
#pragma unroll
    for (int nt = 0; nt < 4; ++nt) accR[mr][nt] = (v4f){0.f, 0.f, 0.f, 0.f};
  gemm_accum<4>(featR, wBreg, Abuf, t, m0, M, accR);

  float bR[4];
#pragma unroll
  for (int f = 0; f < 4; ++f) bR[f] = biasf[loff + 80 + f * 16 + lane15];

  // ======================= DFL: softmax over bins = over 16-lane group =====
  // C-frag col (lane&15) = bin, nt = side, row (kg*4+r) = pixel.
  float d[2][4][4];
#pragma unroll
  for (int mr = 0; mr < 2; ++mr) {
#pragma unroll
    for (int f = 0; f < 4; ++f) {
#pragma unroll
      for (int rr = 0; rr < 4; ++rr) {
        const float xx = accR[mr][f][rr] + bR[f];
        float mx = xx;
        mx = fmaxf(mx, __shfl_xor(mx, 1));
        mx = fmaxf(mx, __shfl_xor(mx, 2));
        mx = fmaxf(mx, __shfl_xor(mx, 4));
        mx = fmaxf(mx, __shfl_xor(mx, 8));
        const float e = __expf(xx - mx);
        float s = e, wq = e * (float)lane15;
        s += __shfl_xor(s, 1); wq += __shfl_xor(wq, 1);
        s += __shfl_xor(s, 2); wq += __shfl_xor(wq, 2);
        s += __shfl_xor(s, 4); wq += __shfl_xor(wq, 4);
        s += __shfl_xor(s, 8); wq += __shfl_xor(wq, 8);
        d[mr][f][rr] = wq * (16.0f / 15.0f) / s;   // proj[q] = 16q/15
      }
    }
  }

  // box -> boxstage (predicated static unroll; every group lane has all sides)
#pragma unroll
  for (int mr = 0; mr < 2; ++mr) {
#pragma unroll
    for (int rr = 0; rr < 4; ++rr) {
      if (lane15 == mr * 4 + rr) {
        const int pl = mbase + mr * 16 + kg * 4 + rr;
        const int pg = m0 + pl;
        const int hh = pg / W;
        const int wc = pg - hh * W;
        const float ax = ((float)wc + 0.5f) * sv;
        const float ay = ((float)hh + 0.5f) * sv;
        v4f bb;
        bb[0] = ax - d[mr][0][rr] * sv;
        bb[1] = ay - d[mr][1][rr] * sv;
        bb[2] = ax + d[mr][2][rr] * sv;
        bb[3] = ay + d[mr][3][rr] * sv;
        *(v4f*)&boxstage[pl * 4] = bb;
      }
    }
  }

  // ======================= cls GEMM (80 outs = 5 n-tiles) ==================
  v4f accC[2][5];
#pragma unroll
  for (int mr = 0; mr < 2; ++mr)
#pragma unroll
    for (int nt = 0; nt < 5; ++nt) accC[mr][nt] = (v4f){0.f, 0.f, 0.f, 0.f};
  gemm_accum<5>(featC, wBcls, Abuf, t, m0, M, accC);
  // gemm_accum's trailing barrier: Abuf reads done -> ostage writes safe

  float bC[5];
#pragma unroll
  for (int nt = 0; nt < 5; ++nt) bC[nt] = biasf[loff + nt * 16 + lane15];

#pragma unroll
  for (int mr = 0; mr < 2; ++mr)
#pragma unroll
    for (int nt = 0; nt < 5; ++nt)
#pragma unroll
      for (int rr = 0; rr < 4; ++rr) {
        const float z = accC[mr][nt][rr] + bC[nt];
        ostage[(mbase + mr * 16 + kg * 4 + rr) * 84 + nt * 16 + lane15] =
            1.f / (1.f + __expf(-z));
      }
  if (t < 128) {
    const v4f bb = *(const v4f*)&boxstage[t * 4];
    *(v4f*)&ostage[t * 84 + 80] = bb;
  }
  __syncthreads();

  // ======================= coalesced store =================================
  float* const obase = out + ((size_t)b * 8400 + moff + m0) * 84;
#pragma unroll
  for (int i = 0; i < 21; ++i) {
    const int p  = i * 256 + t;
    const int fe = p * 2;
    const int m  = fe / 84;
    if (m0 + m < M) {
      *(v2f*)(obase + fe) = *(const v2f*)&ostage[fe];
    }
  }
}

// ---------------------------------------------------------------------------
extern "C" void kernel_launch(void* const* d_in, const int* in_sizes, int n_in,
                              void* d_out, int out_size, void* d_ws, size_t ws_size,
                              hipStream_t stream) {
  const float* cf[3]; const float* rff[3];
  const float* cw[3]; const float* cb[3];
  const float* rw[3]; const float* rb[3];
  for (int i = 0; i < 3; ++i) {
    cf[i]  = (const float*)d_in[i * 6 + 0];
    rff[i] = (const float*)d_in[i * 6 + 1];
    cw[i]  = (const float*)d_in[i * 6 + 2];
    cb[i]  = (const float*)d_in[i * 6 + 3];
    rw[i]  = (const float*)d_in[i * 6 + 4];
    rb[i]  = (const float*)d_in[i * 6 + 5];
  }
  float* o = (float*)d_out;

  // 3*73728 + 432 = 221616 work items -> 866 blocks
  prep_weights<<<dim3(866), dim3(256), 0, stream>>>(
      cw[0], cb[0], rw[0], rb[0],
      cw[1], cb[1], rw[1], rb[1],
      cw[2], cb[2], rw[2], rb[2], d_ws);

  head_kernel<<<dim3(1072), dim3(256), 0, stream>>>(
      cf[0], rff[0], cf[1], rff[1], cf[2], rff[2], d_ws, o);
}